// Round 15
// baseline (213.111 us; speedup 1.0000x reference)
//
#include <hip/hip_runtime.h>
#include <hip/hip_fp16.h>
#include <cstdint>
#include <cstddef>

#define NN 100000
#define NE 1600000
#define D 128
#define NBK 782            // ceil(NN / 128) buckets of 128 nodes
#define NBLK_P 200         // partition blocks (known-best config, R5)
#define EPB 8000           // edges per partition block (200*8000 = 1.6M exact)
#define CAP 3072           // slots per bucket (mean 2048, +22 sigma; overflow clamped)

typedef _Float16 half8 __attribute__((ext_vector_type(8)));
typedef float f32x4 __attribute__((ext_vector_type(4)));

// ---------------- workspace layout (bytes) ----------------
// part  : 782*3072 u32 @ 0         (9,609,216)   read by p4g — h must NOT overlap
// gcnt  : 782*16 u32  @ 9,609,216  (   50,048)   (1 counter/line; memset pre-zeroed)
// z'    : NN*2 f32    @ 25,600,000 (   800,000)
// dinv  : NN f32      @ 26,400,000 (   400,000)
// rp    : NN u32      @ 26,800,000 (   400,000)
// re    : NN u32      @ 27,200,000 (   400,000)
// col   : 782*3072 u32 @ 27,600,000 (9,609,216+256 pad)  bucket-slotted
// Wt    : 128*128 f16 @ 37,300,000 (    32,768)
// h'    : NN*128 f16  @ 40,000,000 (25,600,000)
// R11 lesson: single-pass scatter = 15x write amp. R12: p4g was a 19-barrier
// latency chain. R13: de-serialized p4g -> 212us. R14: coop-fused prologue
// crashes the harness (graph capture) -> reverted to R13, the measured best.

// PSCAT: fused histogram + range-reserve + scatter (measured ~27us at 200x256).
__launch_bounds__(256)
__global__ void pscat_k(const int* __restrict__ ei, unsigned* __restrict__ gcnt,
                        unsigned* __restrict__ part,
                        const float* __restrict__ W, _Float16* __restrict__ Wt) {
    __shared__ unsigned hist[NBK];
    __shared__ unsigned run[NBK];
    int tid = threadIdx.x, b = blockIdx.x;
    for (int k = tid; k < NBK; k += 256) hist[k] = 0u;
    __syncthreads();
    int e0 = b * EPB;
    for (int i = tid * 4; i < EPB; i += 1024) {
        int4 d4 = *(const int4*)(ei + NE + e0 + i);
        atomicAdd(&hist[d4.x >> 7], 1u);
        atomicAdd(&hist[d4.y >> 7], 1u);
        atomicAdd(&hist[d4.z >> 7], 1u);
        atomicAdd(&hist[d4.w >> 7], 1u);
    }
    __syncthreads();
    for (int k = tid; k < NBK; k += 256) {
        unsigned c = hist[k];
        run[k] = c ? atomicAdd(&gcnt[k * 16], c) : 0u;
    }
    if (b < 64) {  // fused Wt transpose+cast, overlaps the atomic latency
        int idx = b * 256 + tid;
        int n = idx >> 7, kk = idx & 127;
        Wt[idx] = (_Float16)W[kk * 128 + n];
    }
    __syncthreads();
    for (int i = tid * 4; i < EPB; i += 1024) {
        int4 s4 = *(const int4*)(ei + e0 + i);
        int4 d4 = *(const int4*)(ei + NE + e0 + i);
        unsigned k, slot;
        k = (unsigned)(d4.x >> 7); slot = atomicAdd(&run[k], 1u);
        if (slot < CAP) part[(size_t)k * CAP + slot] = (unsigned)s4.x | ((unsigned)(d4.x & 127) << 20);
        k = (unsigned)(d4.y >> 7); slot = atomicAdd(&run[k], 1u);
        if (slot < CAP) part[(size_t)k * CAP + slot] = (unsigned)s4.y | ((unsigned)(d4.y & 127) << 20);
        k = (unsigned)(d4.z >> 7); slot = atomicAdd(&run[k], 1u);
        if (slot < CAP) part[(size_t)k * CAP + slot] = (unsigned)s4.z | ((unsigned)(d4.z & 127) << 20);
        k = (unsigned)(d4.w >> 7); slot = atomicAdd(&run[k], 1u);
        if (slot < CAP) part[(size_t)k * CAP + slot] = (unsigned)s4.w | ((unsigned)(d4.w & 127) << 20);
    }
}

// P4G v2: fused CSR-build + GEMM, de-serialized (R12 diagnosis: 48us at 13%
// occupancy = single-block latency chain). vs R9: no xs staging (A-frags
// direct from global x), wave-0 shfl scan (no inner barriers), LDS 36.4KB ->
// 4 blocks/CU, barriers 19 -> 5. Measured: drops out of top-5 (<58.8us).
// Verified MFMA layouts: A[m=lane&15][k=(lane>>4)*8+j], B[k][n=lane&15],
//                        C/D col=lane&15 row=(lane>>4)*4+reg.
__launch_bounds__(256, 4)
__global__ void p4g_k(const unsigned* __restrict__ part, const unsigned* __restrict__ gcnt,
                      const float* __restrict__ x, const _Float16* __restrict__ Wt,
                      unsigned* __restrict__ rp, unsigned* __restrict__ re,
                      float* __restrict__ dinv, unsigned* __restrict__ col,
                      _Float16* __restrict__ h) {
    __shared__ __align__(16) _Float16 wt[128 * 136];  // B: wt[n][k]; reused as epilogue buffer
    __shared__ unsigned cc[128];    // per-node counts
    __shared__ unsigned run[128];   // scatter cursors
    __shared__ float dinvs[128];
    int tid = threadIdx.x, k = blockIdx.x;
    int n0 = k << 7;
    int w = tid >> 6, lane = tid & 63;
    int m = lane & 15, q4 = lane >> 4;

    // stage Wt: 2048 half8 chunks, coalesced global, conflict-free LDS
#pragma unroll
    for (int q = 0; q < 8; q++) {
        int idx = q * 256 + tid;
        int n = idx >> 4, k8 = (idx & 15) * 8;
        *(half8*)(&wt[n * 136 + k8]) = *(const half8*)(Wt + n * 128 + k8);
    }

    unsigned cnt = gcnt[k * 16];
    if (cnt > CAP) cnt = CAP;
    unsigned e0c = (unsigned)k * CAP;
    const unsigned* pk = part + (size_t)k * CAP;

    if (tid < 128) cc[tid] = 0u;
    __syncthreads();                                   // [b1]
    for (unsigned t = tid; t < cnt; t += 256)
        atomicAdd(&cc[(pk[t] >> 20) & 127], 1u);
    __syncthreads();                                   // [b2]

    // wave-0 shfl scan over 128 counters (2/lane), zero inner barriers
    if (tid < 64) {
        unsigned c0 = cc[tid], c1 = cc[64 + tid];
        unsigned v0 = c0, v1 = c1;
#pragma unroll
        for (int off = 1; off < 64; off <<= 1) {
            unsigned u = __shfl_up(v0, off);
            if (tid >= off) v0 += u;
        }
#pragma unroll
        for (int off = 1; off < 64; off <<= 1) {
            unsigned u = __shfl_up(v1, off);
            if (tid >= off) v1 += u;
        }
        v1 += __shfl(v0, 63);                // carry total of first half
        unsigned ex0 = v0 - c0, ex1 = v1 - c1;
        run[tid] = ex0;
        run[64 + tid] = ex1;
        float dv0 = rsqrtf((float)(c0 + 1u));
        float dv1 = rsqrtf((float)(c1 + 1u));
        dinvs[tid] = dv0;
        dinvs[64 + tid] = dv1;
        int g0 = n0 + tid, g1 = n0 + 64 + tid;
        if (g0 < NN) { rp[g0] = e0c + ex0; re[g0] = e0c + ex0 + c0; dinv[g0] = dv0; }
        if (g1 < NN) { rp[g1] = e0c + ex1; re[g1] = e0c + ex1 + c1; dinv[g1] = dv1; }
    }
    __syncthreads();                                   // [b3]

    for (unsigned t = tid; t < cnt; t += 256) {
        unsigned v = pk[t];
        unsigned dlo = (v >> 20) & 127;
        unsigned pos = e0c + atomicAdd(&run[dlo], 1u);
        col[pos] = v & 0xFFFFFu;
    }
    // no barrier: gemm below touches only wt (staged pre-b1) and x/registers

    // gemm: 4 waves, wave w owns rows w*32..w*32+31; A-frags direct from x.
    int r0 = n0 + w * 32 + m;
    int r1 = r0 + 16;
    bool ok0 = r0 < NN, ok1 = r1 < NN;
    const float* xr0 = x + (size_t)r0 * 128 + q4 * 8;
    const float* xr1 = x + (size_t)r1 * 128 + q4 * 8;

    f32x4 acc[2][8];
#pragma unroll
    for (int rt = 0; rt < 2; rt++)
#pragma unroll
        for (int nt = 0; nt < 8; nt++) acc[rt][nt] = (f32x4){0.f, 0.f, 0.f, 0.f};

#pragma unroll
    for (int ks = 0; ks < 128; ks += 32) {
        float4 f00 = ok0 ? *(const float4*)(xr0 + ks)     : make_float4(0, 0, 0, 0);
        float4 f01 = ok0 ? *(const float4*)(xr0 + ks + 4) : make_float4(0, 0, 0, 0);
        float4 f10 = ok1 ? *(const float4*)(xr1 + ks)     : make_float4(0, 0, 0, 0);
        float4 f11 = ok1 ? *(const float4*)(xr1 + ks + 4) : make_float4(0, 0, 0, 0);
        half8 a0 = { (_Float16)f00.x, (_Float16)f00.y, (_Float16)f00.z, (_Float16)f00.w,
                     (_Float16)f01.x, (_Float16)f01.y, (_Float16)f01.z, (_Float16)f01.w };
        half8 a1 = { (_Float16)f10.x, (_Float16)f10.y, (_Float16)f10.z, (_Float16)f10.w,
                     (_Float16)f11.x, (_Float16)f11.y, (_Float16)f11.z, (_Float16)f11.w };
#pragma unroll
        for (int nt = 0; nt < 8; nt++) {
            half8 bf = *(const half8*)(&wt[(nt * 16 + m) * 136 + ks + q4 * 8]);
            acc[0][nt] = __builtin_amdgcn_mfma_f32_16x16x32_f16(a0, bf, acc[0][nt], 0, 0, 0);
            acc[1][nt] = __builtin_amdgcn_mfma_f32_16x16x32_f16(a1, bf, acc[1][nt], 0, 0, 0);
        }
    }

    // epilogue: scale by dinv (LDS), fp16, stage in wt (dead), coalesced store
    float dv[2][4];
#pragma unroll
    for (int rt = 0; rt < 2; rt++)
#pragma unroll
        for (int r = 0; r < 4; r++)
            dv[rt][r] = dinvs[w * 32 + rt * 16 + q4 * 4 + r];
    __syncthreads();                                   // [b4] wt reads + scatter done
#pragma unroll
    for (int rt = 0; rt < 2; rt++)
#pragma unroll
        for (int nt = 0; nt < 8; nt++)
#pragma unroll
            for (int r = 0; r < 4; r++)
                wt[(w * 32 + rt * 16 + q4 * 4 + r) * 136 + nt * 16 + m] =
                    (_Float16)(acc[rt][nt][r] * dv[rt][r]);
    __syncthreads();                                   // [b5]
#pragma unroll
    for (int q = 0; q < 8; q++) {
        int idx = q * 256 + tid;
        int row = idx >> 4;
        int c8 = (idx & 15) * 8;
        int gr = n0 + row;
        if (gr < NN)
            *(half8*)(h + (size_t)gr * 128 + c8) = *(const half8*)(&wt[row * 136 + c8]);
    }
}

// Layer-1 aggregation of prescaled h' + bias/ReLU + 128x2 W2 projection.
// One wave per node; lane holds half2 (4B chunk; 64 lanes = full 256B row).
// Measured at the fill-path roofline (58.9us vs 193MB/3.37TB/s = 57us).
__launch_bounds__(256)
__global__ void agg1_k(const _Float16* __restrict__ h, const unsigned* __restrict__ rp,
                       const unsigned* __restrict__ re, const unsigned* __restrict__ col,
                       const float* __restrict__ dinv, const float* __restrict__ b1,
                       const float* __restrict__ W2, float* __restrict__ z) {
    int i = (blockIdx.x * 256 + threadIdx.x) >> 6;
    int lane = threadIdx.x & 63;
    if (i >= NN) return;
    unsigned si = __builtin_amdgcn_readfirstlane((unsigned)i);  // force SGPR

    const __half2* hb = (const __half2*)h;
    unsigned p0 = __builtin_amdgcn_readfirstlane(rp[si]);
    unsigned p1 = __builtin_amdgcn_readfirstlane(re[si]);
    int deg = (int)(p1 - p0);

    // col window: one per-lane load covers up to 64 edge ids. May read past p1
    // (stays inside the padded slotted col); unused lanes masked by (k<degc).
    unsigned cv = col[p0 + (unsigned)lane];

    int degc = deg > 64 ? 64 : deg;
    int R = (degc + 15) >> 4;                 // full 16-rounds incl. padding
    float2 sv = __half22float2(hb[(size_t)si * 64u + lane]);
    float f = (float)(1 + degc - 16 * R);     // corrects padding reads of row si
    float ax = f * sv.x, ay = f * sv.y;

#define ROUND16(r)                                                           \
    {                                                                        \
        float2 vv[16];                                                       \
        _Pragma("unroll")                                                    \
        for (int t = 0; t < 16; t++) {                                       \
            int k = (r) * 16 + t;                                            \
            unsigned s = (k < degc) ? __builtin_amdgcn_readlane(cv, k) : si; \
            vv[t] = __half22float2(hb[(size_t)s * 64u + lane]);              \
        }                                                                    \
        ax += ((vv[0].x + vv[1].x) + (vv[2].x + vv[3].x))                    \
            + ((vv[4].x + vv[5].x) + (vv[6].x + vv[7].x))                    \
            + ((vv[8].x + vv[9].x) + (vv[10].x + vv[11].x))                  \
            + ((vv[12].x + vv[13].x) + (vv[14].x + vv[15].x));               \
        ay += ((vv[0].y + vv[1].y) + (vv[2].y + vv[3].y))                    \
            + ((vv[4].y + vv[5].y) + (vv[6].y + vv[7].y))                    \
            + ((vv[8].y + vv[9].y) + (vv[10].y + vv[11].y))                  \
            + ((vv[12].y + vv[13].y) + (vv[14].y + vv[15].y));               \
    }

    if (degc > 0)  ROUND16(0)
    if (degc > 16) ROUND16(1)
    if (degc > 32) ROUND16(2)
    if (degc > 48) ROUND16(3)
#undef ROUND16

    // deg > 64 remainder (Poisson(16): essentially never taken)
    for (unsigned e = p0 + 64; e < p1; ++e) {
        unsigned s_ = __builtin_amdgcn_readfirstlane(col[e]);
        float2 v = __half22float2(hb[(size_t)s_ * 64u + lane]);
        ax += v.x;
        ay += v.y;
    }

    float di = dinv[si];
    ax *= di;
    ay *= di;

    float2 bv = ((const float2*)b1)[lane];
    float h0 = fmaxf(ax + bv.x, 0.f);
    float h1 = fmaxf(ay + bv.y, 0.f);

    float4 w = ((const float4*)W2)[lane];
    float pz0 = fmaf(h0, w.x, h1 * w.z);
    float pz1 = fmaf(h0, w.y, h1 * w.w);
#pragma unroll
    for (int off = 32; off > 0; off >>= 1) {
        pz0 += __shfl_down(pz0, off);
        pz1 += __shfl_down(pz1, off);
    }
    if (lane == 0) {
        float2* zp = (float2*)(z + (size_t)si * 2);
        *zp = make_float2(pz0 * di, pz1 * di);  // prescale for layer-2 aggregation
    }
}

// Layer-2 aggregation over prescaled z'. 16 lanes per node (avg degree 16):
// 4 nodes/wave, width-16 shuffle reduce. out[i] = (Σ z'[s] + z'[i])*dinv[i] + b2.
__launch_bounds__(256)
__global__ void agg2_k(const float* __restrict__ z, const unsigned* __restrict__ rp,
                       const unsigned* __restrict__ re, const unsigned* __restrict__ col,
                       const float* __restrict__ dinv, const float* __restrict__ b2,
                       float* __restrict__ out) {
    int i = (blockIdx.x * 256 + threadIdx.x) >> 4;
    int sl = threadIdx.x & 15;
    if (i >= NN) return;

    unsigned p0 = rp[i], p1 = re[i];
    float a0 = 0.f, a1 = 0.f;
    for (unsigned e = p0 + sl; e < p1; e += 16) {
        unsigned s = col[e];
        float2 v = ((const float2*)z)[s];
        a0 += v.x;
        a1 += v.y;
    }
#pragma unroll
    for (int off = 8; off > 0; off >>= 1) {
        a0 += __shfl_down(a0, off, 16);
        a1 += __shfl_down(a1, off, 16);
    }
    if (sl == 0) {
        float di = dinv[i];
        float2 zi = ((const float2*)z)[i];
        out[(size_t)i * 2]     = (a0 + zi.x) * di + b2[0];
        out[(size_t)i * 2 + 1] = (a1 + zi.y) * di + b2[1];
    }
}

extern "C" void kernel_launch(void* const* d_in, const int* in_sizes, int n_in,
                              void* d_out, int out_size, void* d_ws, size_t ws_size,
                              hipStream_t stream) {
    const float* x  = (const float*)d_in[0];
    const int*   ei = (const int*)d_in[1];
    const float* W1 = (const float*)d_in[2];
    const float* b1 = (const float*)d_in[3];
    const float* W2 = (const float*)d_in[4];
    const float* b2 = (const float*)d_in[5];
    float* out = (float*)d_out;

    char* ws = (char*)d_ws;
    unsigned* part = (unsigned*)(ws);
    unsigned* gcnt = (unsigned*)(ws + 9609216);
    float*    z    = (float*)(ws + 25600000);
    float*    dinv = (float*)(ws + 26400000);
    unsigned* rp   = (unsigned*)(ws + 26800000);
    unsigned* re   = (unsigned*)(ws + 27200000);
    unsigned* col  = (unsigned*)(ws + 27600000);
    _Float16* Wt   = (_Float16*)(ws + 37300000);
    _Float16* h    = (_Float16*)(ws + 40000000);

    hipMemsetAsync(gcnt, 0, 782 * 16 * sizeof(unsigned), stream);
    pscat_k<<<NBLK_P, 256, 0, stream>>>(ei, gcnt, part, W1, Wt);
    p4g_k<<<NBK, 256, 0, stream>>>(part, gcnt, x, Wt, rp, re, dinv, col, h);
    agg1_k<<<(NN * 64 + 255) / 256, 256, 0, stream>>>(h, rp, re, col, dinv, b1, W2, z);
    agg2_k<<<(NN * 16 + 255) / 256, 256, 0, stream>>>(z, rp, re, col, dinv, b2, out);
}